// Round 1
// baseline (1579.467 us; speedup 1.0000x reference)
//
#include <hip/hip_runtime.h>

// GraphNN_KNN: N=50000 nodes, E=800000 edges, H=64.
// Algebraic restructure: per-edge MLP msg = relu([x_i, x_j-x_i, ef] @ W + b)
//   == relu(u[dst] + v[src] + ef*we)  with  u = x@(Wt-Wm)+b, v = x@Wm
// so all GEMMs are dense per-node N x 64 x 64; edge passes are gather+reduce
// over prebuilt per-node edge lists (no atomics in hot path).

#define NN 50000
#define NE 800000
#define PER 200000   // E / 4 orders
#define HD 64
#define PAD_EM 32    // Poisson(4) per (order,src): P(deg>32) ~ 0
#define PAD_EC 64    // Poisson(16) per dst: P(deg>64) ~ 0

// ---------------- edge-list build (once per launch) ----------------
__global__ __launch_bounds__(256) void build_lists(
        const int* __restrict__ ei,
        int* __restrict__ cnt_em, int* __restrict__ cnt_dst,
        int* __restrict__ em_list, int* __restrict__ ec_list) {
    int e = blockIdx.x * 256 + threadIdx.x;
    if (e >= NE) return;
    int src = ei[e];
    int dst = ei[NE + e];
    int o = e / PER;
    int s1 = atomicAdd(&cnt_em[o * NN + src], 1);
    if (s1 < PAD_EM) em_list[(size_t)(o * NN + src) * PAD_EM + s1] = e;
    int s2 = atomicAdd(&cnt_dst[dst], 1);
    if (s2 < PAD_EC) ec_list[(size_t)dst * PAD_EC + s2] = e;
}

// ---------------- linear layer: x = relu((fold? (x+agg)/2 : x) @ W + b) ----
// TILE = 64 nodes per block, 256 threads, F = 64 outputs.
template<int K, bool FOLD>
__global__ __launch_bounds__(256) void lin_kernel(
        const float* __restrict__ xin, const float* __restrict__ agg,
        const float* __restrict__ W, const float* __restrict__ bias,
        float* __restrict__ xout) {
    __shared__ float xs[64][K + 1];
    int t = threadIdx.x;
    int n0 = blockIdx.x * 64;
    for (int idx = t; idx < 64 * K; idx += 256) {
        int n = idx / K, k = idx - n * K;
        int g = n0 + n;
        float xv = 0.f;
        if (g < NN) {
            xv = xin[(size_t)g * K + k];
            if (FOLD) xv = (xv + agg[(size_t)g * HD + k]) * 0.5f;
        }
        xs[n][k] = xv;
    }
    __syncthreads();
    int ng = t >> 4;
    int f0 = (t & 15) * 4;
    float acc[4][4] = {};
    for (int k = 0; k < K; ++k) {
        float4 w4 = *(const float4*)&W[k * HD + f0];
        #pragma unroll
        for (int j = 0; j < 4; ++j) {
            float xv = xs[ng * 4 + j][k];
            acc[j][0] += xv * w4.x; acc[j][1] += xv * w4.y;
            acc[j][2] += xv * w4.z; acc[j][3] += xv * w4.w;
        }
    }
    float4 b4 = *(const float4*)&bias[f0];
    #pragma unroll
    for (int j = 0; j < 4; ++j) {
        int g = n0 + ng * 4 + j;
        if (g < NN) {
            float4 o;
            o.x = fmaxf(acc[j][0] + b4.x, 0.f);
            o.y = fmaxf(acc[j][1] + b4.y, 0.f);
            o.z = fmaxf(acc[j][2] + b4.z, 0.f);
            o.w = fmaxf(acc[j][3] + b4.w, 0.f);
            *(float4*)&xout[(size_t)g * HD + f0] = o;
        }
    }
}

// ---------------- u/v precompute: u = xeff@(Wt-Wm)+b, v = xeff@Wm ---------
// FOLD: xeff = (x+agg)/2, written back to xw. W has rows [0:64]=Wt, [64:128]=Wm.
template<bool FOLD>
__global__ __launch_bounds__(256) void uv_kernel(
        const float* __restrict__ xin, const float* __restrict__ agg,
        float* __restrict__ xw,
        const float* __restrict__ W, const float* __restrict__ bias,
        float* __restrict__ u, float* __restrict__ v) {
    __shared__ float xs[64][65];
    int t = threadIdx.x;
    int n0 = blockIdx.x * 64;
    for (int idx = t; idx < 64 * 64; idx += 256) {
        int n = idx >> 6, k = idx & 63;
        int g = n0 + n;
        float xv = 0.f;
        if (g < NN) {
            xv = xin[(size_t)g * HD + k];
            if (FOLD) {
                xv = (xv + agg[(size_t)g * HD + k]) * 0.5f;
                xw[(size_t)g * HD + k] = xv;
            }
        }
        xs[n][k] = xv;
    }
    __syncthreads();
    int ng = t >> 4;
    int f0 = (t & 15) * 4;
    float acca[4][4] = {};
    float accv[4][4] = {};
    for (int k = 0; k < 64; ++k) {
        float4 wt = *(const float4*)&W[k * HD + f0];
        float4 wm = *(const float4*)&W[(64 + k) * HD + f0];
        #pragma unroll
        for (int j = 0; j < 4; ++j) {
            float xv = xs[ng * 4 + j][k];
            acca[j][0] += xv * wt.x; acca[j][1] += xv * wt.y;
            acca[j][2] += xv * wt.z; acca[j][3] += xv * wt.w;
            accv[j][0] += xv * wm.x; accv[j][1] += xv * wm.y;
            accv[j][2] += xv * wm.z; accv[j][3] += xv * wm.w;
        }
    }
    float4 b4 = *(const float4*)&bias[f0];
    #pragma unroll
    for (int j = 0; j < 4; ++j) {
        int g = n0 + ng * 4 + j;
        if (g < NN) {
            float4 uo, vo;
            uo.x = acca[j][0] - accv[j][0] + b4.x;
            uo.y = acca[j][1] - accv[j][1] + b4.y;
            uo.z = acca[j][2] - accv[j][2] + b4.z;
            uo.w = acca[j][3] - accv[j][3] + b4.w;
            vo.x = accv[j][0]; vo.y = accv[j][1];
            vo.z = accv[j][2]; vo.w = accv[j][3];
            *(float4*)&u[(size_t)g * HD + f0] = uo;
            *(float4*)&v[(size_t)g * HD + f0] = vo;
        }
    }
}

// ---------------- emulsion edge pass: agg[n] = sum_e relu(u[dst]+v[n]+ef*we)
// one wave per node, lane = feature. Writes agg fully (0 for empty nodes).
__global__ __launch_bounds__(256) void em_edge(
        const int* __restrict__ ei, const float* __restrict__ ef,
        const int* __restrict__ cnt_em, const int* __restrict__ em_list,
        const float* __restrict__ u, const float* __restrict__ v,
        const float* __restrict__ we, float* __restrict__ agg, int order) {
    int wid = (blockIdx.x * 256 + threadIdx.x) >> 6;
    int lane = threadIdx.x & 63;
    if (wid >= NN) return;
    int deg = min(cnt_em[order * NN + wid], PAD_EM);
    float vn = v[(size_t)wid * HD + lane];
    float wef = we[lane];
    const int* __restrict__ lst = &em_list[(size_t)(order * NN + wid) * PAD_EM];
    float acc = 0.f;
    for (int j = 0; j < deg; ++j) {
        int e = lst[j];
        int dst = ei[NE + e];
        float efe = ef[e];
        float m = u[(size_t)dst * HD + lane] + vn + efe * wef;
        acc += fmaxf(m, 0.f);
    }
    agg[(size_t)wid * HD + lane] = acc;
}

// ---------------- edge conv pass: x[n] = max(0, max_e (u[n]+v[src])) -------
__global__ __launch_bounds__(256) void ec_edge(
        const int* __restrict__ ei,
        const int* __restrict__ cnt_dst, const int* __restrict__ ec_list,
        const float* __restrict__ u, const float* __restrict__ v,
        float* __restrict__ xout) {
    int wid = (blockIdx.x * 256 + threadIdx.x) >> 6;
    int lane = threadIdx.x & 63;
    if (wid >= NN) return;
    int deg = min(cnt_dst[wid], PAD_EC);
    float un = u[(size_t)wid * HD + lane];
    const int* __restrict__ lst = &ec_list[(size_t)wid * PAD_EC];
    float m = 0.f;  // empty segment -> 0; relu'd msgs >= 0, so init 0 is exact
    for (int j = 0; j < deg; ++j) {
        int e = lst[j];
        int s = ei[e];
        m = fmaxf(m, fmaxf(un + v[(size_t)s * HD + lane], 0.f));
    }
    xout[(size_t)wid * HD + lane] = m;
}

// ---------------- output projection: out = x @ out_w + out_b ---------------
__global__ __launch_bounds__(256) void out_kernel(
        const float* __restrict__ x, const float* __restrict__ W,
        const float* __restrict__ bias, float* __restrict__ out) {
    int n = blockIdx.x * 256 + threadIdx.x;
    if (n >= NN) return;
    float xr[HD];
    #pragma unroll
    for (int k = 0; k < HD; k += 4) {
        float4 t4 = *(const float4*)&x[(size_t)n * HD + k];
        xr[k] = t4.x; xr[k + 1] = t4.y; xr[k + 2] = t4.z; xr[k + 3] = t4.w;
    }
    #pragma unroll
    for (int f = 0; f < 10; ++f) {
        float acc = bias[f];
        #pragma unroll
        for (int k = 0; k < HD; ++k) acc += xr[k] * W[k * 10 + f];
        out[(size_t)n * 10 + f] = acc;
    }
}

extern "C" void kernel_launch(void* const* d_in, const int* in_sizes, int n_in,
                              void* d_out, int out_size, void* d_ws, size_t ws_size,
                              hipStream_t stream) {
    const float* x_in  = (const float*)d_in[0];
    const int*   ei    = (const int*)d_in[1];
    const float* ef    = (const float*)d_in[2];
    const float* lw[3] = {(const float*)d_in[3], (const float*)d_in[5], (const float*)d_in[7]};
    const float* lb[3] = {(const float*)d_in[4], (const float*)d_in[6], (const float*)d_in[8]};
    const float* em_w  = (const float*)d_in[9];
    const float* em_b  = (const float*)d_in[10];
    const float* ec_w  = (const float*)d_in[11];
    const float* ec_b  = (const float*)d_in[12];
    const float* ow    = (const float*)d_in[13];
    const float* ob    = (const float*)d_in[14];
    float* out = (float*)d_out;

    // workspace carve (~91 MB)
    char* wsb = (char*)d_ws;
    size_t off = 0;
    auto alloc = [&](size_t bytes) {
        void* p = wsb + off;
        off = (off + bytes + 255) & ~(size_t)255;
        return p;
    };
    float* x      = (float*)alloc((size_t)NN * HD * 4);
    float* u      = (float*)alloc((size_t)NN * HD * 4);
    float* v      = (float*)alloc((size_t)NN * HD * 4);
    float* agg    = (float*)alloc((size_t)NN * HD * 4);
    int* cnt_em   = (int*)alloc((size_t)4 * NN * 4);
    int* cnt_dst  = (int*)alloc((size_t)NN * 4);
    int* em_list  = (int*)alloc((size_t)4 * NN * PAD_EM * 4);
    int* ec_list  = (int*)alloc((size_t)NN * PAD_EC * 4);
    (void)ws_size; (void)in_sizes; (void)n_in; (void)out_size;

    const int gb_nodes = (NN + 63) / 64;        // 782
    const int gb_edges = (NE + 255) / 256;      // 3125
    const int gb_nwave = (NN * 64 + 255) / 256; // 12500

    hipMemsetAsync(cnt_em, 0, (size_t)4 * NN * 4, stream);
    hipMemsetAsync(cnt_dst, 0, (size_t)NN * 4, stream);
    build_lists<<<gb_edges, 256, 0, stream>>>(ei, cnt_em, cnt_dst, em_list, ec_list);

    // x = relu(x_in @ lin0_w + lin0_b)
    lin_kernel<10, false><<<gb_nodes, 256, 0, stream>>>(x_in, nullptr, lw[0], lb[0], x);

    for (int i = 0; i < 3; ++i) {
        const float* Wi = em_w + (size_t)i * 129 * HD;
        const float* bi = em_b + (size_t)i * HD;
        for (int o = 0; o < 4; ++o) {
            if (o == 0)
                uv_kernel<false><<<gb_nodes, 256, 0, stream>>>(x, nullptr, nullptr, Wi, bi, u, v);
            else
                uv_kernel<true><<<gb_nodes, 256, 0, stream>>>(x, agg, x, Wi, bi, u, v);
            em_edge<<<gb_nwave, 256, 0, stream>>>(ei, ef, cnt_em, em_list, u, v,
                                                  Wi + 128 * HD, agg, o);
        }
        if (i < 2)  // x = relu(((x+agg)/2) @ lin_w + lin_b)
            lin_kernel<64, true><<<gb_nodes, 256, 0, stream>>>(x, agg, lw[i + 1], lb[i + 1], x);
    }

    for (int j = 0; j < 3; ++j) {
        const float* Wj = ec_w + (size_t)j * 128 * HD;
        const float* bj = ec_b + (size_t)j * HD;
        if (j == 0)  // fold pending agg from last emulsion order
            uv_kernel<true><<<gb_nodes, 256, 0, stream>>>(x, agg, x, Wj, bj, u, v);
        else
            uv_kernel<false><<<gb_nodes, 256, 0, stream>>>(x, nullptr, nullptr, Wj, bj, u, v);
        ec_edge<<<gb_nwave, 256, 0, stream>>>(ei, cnt_dst, ec_list, u, v, x);
    }

    out_kernel<<<(NN + 255) / 256, 256, 0, stream>>>(x, ow, ob, out);
}

// Round 2
// 1379.002 us; speedup vs baseline: 1.1454x; 1.1454x over previous
//
#include <hip/hip_runtime.h>
#include <hip/hip_fp16.h>

// GraphNN_KNN: N=50000 nodes, E=800000 edges, H=64.
// msg = relu([x_i, x_j-x_i, ef] @ W + b) == relu(u[dst] + v[src] + ef*we)
// with u = x@(Wt-Wm)+b, v = x@Wm. Node GEMMs dense fp32; edge passes gather
// fp16 u/v rows via exact CSR lists (payload packed into the list values).

#define NN 50000
#define NE 800000
#define PER 200000      // E / 4 orders
#define HD 64
#define NKEY 250112     // 4*NN em keys + NN ec keys, padded to 977*256

// ---------------- CSR build ----------------
__global__ __launch_bounds__(256) void count_kernel(
        const int* __restrict__ ei, int* __restrict__ cnt) {
    int e = blockIdx.x * 256 + threadIdx.x;
    if (e >= NE) return;
    int src = ei[e];
    int dst = ei[NE + e];
    int o = e / PER;
    atomicAdd(&cnt[o * NN + src], 1);
    atomicAdd(&cnt[4 * NN + dst], 1);
}

// block sums for hierarchical scan
__global__ __launch_bounds__(256) void scan_blk(
        const int* __restrict__ cnt, int* __restrict__ bsum) {
    __shared__ int s[256];
    int t = threadIdx.x;
    int i = blockIdx.x * 256 + t;
    int c = (i < NKEY) ? cnt[i] : 0;
    s[t] = c; __syncthreads();
    for (int d = 1; d < 256; d <<= 1) {
        int v = (t >= d) ? s[t - d] : 0;
        __syncthreads(); s[t] += v; __syncthreads();
    }
    if (t == 255) bsum[blockIdx.x] = s[255];
}

__global__ __launch_bounds__(1024) void scan_top(
        const int* __restrict__ bsum, int* __restrict__ bofs, int nb) {
    __shared__ int s[1024];
    int t = threadIdx.x;
    int c = (t < nb) ? bsum[t] : 0;
    s[t] = c; __syncthreads();
    for (int d = 1; d < 1024; d <<= 1) {
        int v = (t >= d) ? s[t - d] : 0;
        __syncthreads(); s[t] += v; __syncthreads();
    }
    if (t < nb) bofs[t] = s[t] - c;  // exclusive
}

__global__ __launch_bounds__(256) void scan_fin(
        const int* __restrict__ cnt, const int* __restrict__ bofs,
        int* __restrict__ ofs) {
    __shared__ int s[256];
    int t = threadIdx.x;
    int i = blockIdx.x * 256 + t;
    int c = (i < NKEY) ? cnt[i] : 0;
    s[t] = c; __syncthreads();
    for (int d = 1; d < 256; d <<= 1) {
        int v = (t >= d) ? s[t - d] : 0;
        __syncthreads(); s[t] += v; __syncthreads();
    }
    if (i < NKEY) ofs[i] = bofs[blockIdx.x] + s[t] - c;  // exclusive
}

// fill: em values = {dst, ef_bits} (8B), ec values = src (4B)
__global__ __launch_bounds__(256) void fill_kernel(
        const int* __restrict__ ei, const float* __restrict__ ef,
        int* __restrict__ cursor, int2* __restrict__ em_val,
        int* __restrict__ ec_val) {
    int e = blockIdx.x * 256 + threadIdx.x;
    if (e >= NE) return;
    int src = ei[e];
    int dst = ei[NE + e];
    int o = e / PER;
    int p1 = atomicAdd(&cursor[o * NN + src], 1);
    int2 pv; pv.x = dst; pv.y = __float_as_int(ef[e]);
    em_val[p1] = pv;
    int p2 = atomicAdd(&cursor[4 * NN + dst], 1) - NE;
    ec_val[p2] = src;
}

// ---------------- linear: x = relu((fold? (x+agg)/2 : x) @ W + b) ----------
template<int K, bool FOLD>
__global__ __launch_bounds__(256) void lin_kernel(
        const float* __restrict__ xin, const float* __restrict__ agg,
        const float* __restrict__ W, const float* __restrict__ bias,
        float* __restrict__ xout) {
    __shared__ float xs[64][K + 1];
    int t = threadIdx.x;
    int n0 = blockIdx.x * 64;
    for (int idx = t; idx < 64 * K; idx += 256) {
        int n = idx / K, k = idx - n * K;
        int g = n0 + n;
        float xv = 0.f;
        if (g < NN) {
            xv = xin[(size_t)g * K + k];
            if (FOLD) xv = (xv + agg[(size_t)g * HD + k]) * 0.5f;
        }
        xs[n][k] = xv;
    }
    __syncthreads();
    int ng = t >> 4;
    int f0 = (t & 15) * 4;
    float acc[4][4] = {};
    for (int k = 0; k < K; ++k) {
        float4 w4 = *(const float4*)&W[k * HD + f0];
        #pragma unroll
        for (int j = 0; j < 4; ++j) {
            float xv = xs[ng * 4 + j][k];
            acc[j][0] += xv * w4.x; acc[j][1] += xv * w4.y;
            acc[j][2] += xv * w4.z; acc[j][3] += xv * w4.w;
        }
    }
    float4 b4 = *(const float4*)&bias[f0];
    #pragma unroll
    for (int j = 0; j < 4; ++j) {
        int g = n0 + ng * 4 + j;
        if (g < NN) {
            float4 o;
            o.x = fmaxf(acc[j][0] + b4.x, 0.f);
            o.y = fmaxf(acc[j][1] + b4.y, 0.f);
            o.z = fmaxf(acc[j][2] + b4.z, 0.f);
            o.w = fmaxf(acc[j][3] + b4.w, 0.f);
            *(float4*)&xout[(size_t)g * HD + f0] = o;
        }
    }
}

// ---------------- u/v precompute (fp16 outputs) ----------------------------
// u = xeff@(Wt-Wm)+b, v = xeff@Wm. FOLD: xeff=(x+agg)/2 written back to xw.
template<bool FOLD>
__global__ __launch_bounds__(256) void uv_kernel(
        const float* __restrict__ xin, const float* __restrict__ agg,
        float* __restrict__ xw,
        const float* __restrict__ W, const float* __restrict__ bias,
        __half* __restrict__ u, __half* __restrict__ v) {
    __shared__ float xs[64][65];
    int t = threadIdx.x;
    int n0 = blockIdx.x * 64;
    for (int idx = t; idx < 64 * 64; idx += 256) {
        int n = idx >> 6, k = idx & 63;
        int g = n0 + n;
        float xv = 0.f;
        if (g < NN) {
            xv = xin[(size_t)g * HD + k];
            if (FOLD) {
                xv = (xv + agg[(size_t)g * HD + k]) * 0.5f;
                xw[(size_t)g * HD + k] = xv;
            }
        }
        xs[n][k] = xv;
    }
    __syncthreads();
    int ng = t >> 4;
    int f0 = (t & 15) * 4;
    float acca[4][4] = {};
    float accv[4][4] = {};
    for (int k = 0; k < 64; ++k) {
        float4 wt = *(const float4*)&W[k * HD + f0];
        float4 wm = *(const float4*)&W[(64 + k) * HD + f0];
        #pragma unroll
        for (int j = 0; j < 4; ++j) {
            float xv = xs[ng * 4 + j][k];
            acca[j][0] += xv * wt.x; acca[j][1] += xv * wt.y;
            acca[j][2] += xv * wt.z; acca[j][3] += xv * wt.w;
            accv[j][0] += xv * wm.x; accv[j][1] += xv * wm.y;
            accv[j][2] += xv * wm.z; accv[j][3] += xv * wm.w;
        }
    }
    float4 b4 = *(const float4*)&bias[f0];
    #pragma unroll
    for (int j = 0; j < 4; ++j) {
        int g = n0 + ng * 4 + j;
        if (g < NN) {
            ushort4 uo, vo;
            uo.x = __half_as_ushort(__float2half_rn(acca[j][0] - accv[j][0] + b4.x));
            uo.y = __half_as_ushort(__float2half_rn(acca[j][1] - accv[j][1] + b4.y));
            uo.z = __half_as_ushort(__float2half_rn(acca[j][2] - accv[j][2] + b4.z));
            uo.w = __half_as_ushort(__float2half_rn(acca[j][3] - accv[j][3] + b4.w));
            vo.x = __half_as_ushort(__float2half_rn(accv[j][0]));
            vo.y = __half_as_ushort(__float2half_rn(accv[j][1]));
            vo.z = __half_as_ushort(__float2half_rn(accv[j][2]));
            vo.w = __half_as_ushort(__float2half_rn(accv[j][3]));
            *(ushort4*)&u[(size_t)g * HD + f0] = uo;
            *(ushort4*)&v[(size_t)g * HD + f0] = vo;
        }
    }
}

// ---------------- emulsion edge pass: agg[n] = sum_e relu(u[dst]+v[n]+ef*we)
__global__ __launch_bounds__(256) void em_edge(
        const int2* __restrict__ em_val, const int* __restrict__ ofs,
        const __half* __restrict__ u, const __half* __restrict__ v,
        const float* __restrict__ we, float* __restrict__ agg, int order) {
    int wid = (blockIdx.x * 256 + threadIdx.x) >> 6;
    int lane = threadIdx.x & 63;
    if (wid >= NN) return;
    int key = order * NN + wid;
    int s0 = ofs[key], s1 = ofs[key + 1];
    float vn = __half2float(v[(size_t)wid * HD + lane]);
    float wef = we[lane];
    float acc = 0.f;
    for (int p = s0; p < s1; ++p) {
        int2 pv = em_val[p];
        float m = __half2float(u[(size_t)pv.x * HD + lane]) + vn
                  + __int_as_float(pv.y) * wef;
        acc += fmaxf(m, 0.f);
    }
    agg[(size_t)wid * HD + lane] = acc;
}

// ---------------- edge conv pass: x[n] = max(0, max_e relu(u[n]+v[src])) ---
__global__ __launch_bounds__(256) void ec_edge(
        const int* __restrict__ ec_val, const int* __restrict__ ofs,
        const __half* __restrict__ u, const __half* __restrict__ v,
        float* __restrict__ xout) {
    int wid = (blockIdx.x * 256 + threadIdx.x) >> 6;
    int lane = threadIdx.x & 63;
    if (wid >= NN) return;
    int s0 = ofs[4 * NN + wid] - NE, s1 = ofs[4 * NN + wid + 1] - NE;
    float un = __half2float(u[(size_t)wid * HD + lane]);
    float m = 0.f;  // empty segment -> 0; relu'd msgs >= 0, init 0 exact
    for (int p = s0; p < s1; ++p) {
        int s = ec_val[p];
        m = fmaxf(m, un + __half2float(v[(size_t)s * HD + lane]));
    }
    xout[(size_t)wid * HD + lane] = m;
}

// ---------------- output projection ----------------------------------------
__global__ __launch_bounds__(256) void out_kernel(
        const float* __restrict__ x, const float* __restrict__ W,
        const float* __restrict__ bias, float* __restrict__ out) {
    int n = blockIdx.x * 256 + threadIdx.x;
    if (n >= NN) return;
    float xr[HD];
    #pragma unroll
    for (int k = 0; k < HD; k += 4) {
        float4 t4 = *(const float4*)&x[(size_t)n * HD + k];
        xr[k] = t4.x; xr[k + 1] = t4.y; xr[k + 2] = t4.z; xr[k + 3] = t4.w;
    }
    #pragma unroll
    for (int f = 0; f < 10; ++f) {
        float acc = bias[f];
        #pragma unroll
        for (int k = 0; k < HD; ++k) acc += xr[k] * W[k * 10 + f];
        out[(size_t)n * 10 + f] = acc;
    }
}

extern "C" void kernel_launch(void* const* d_in, const int* in_sizes, int n_in,
                              void* d_out, int out_size, void* d_ws, size_t ws_size,
                              hipStream_t stream) {
    const float* x_in  = (const float*)d_in[0];
    const int*   ei    = (const int*)d_in[1];
    const float* ef    = (const float*)d_in[2];
    const float* lw[3] = {(const float*)d_in[3], (const float*)d_in[5], (const float*)d_in[7]};
    const float* lb[3] = {(const float*)d_in[4], (const float*)d_in[6], (const float*)d_in[8]};
    const float* em_w  = (const float*)d_in[9];
    const float* em_b  = (const float*)d_in[10];
    const float* ec_w  = (const float*)d_in[11];
    const float* ec_b  = (const float*)d_in[12];
    const float* ow    = (const float*)d_in[13];
    const float* ob    = (const float*)d_in[14];
    float* out = (float*)d_out;

    char* wsb = (char*)d_ws;
    size_t off = 0;
    auto alloc = [&](size_t bytes) {
        void* p = wsb + off;
        off = (off + bytes + 255) & ~(size_t)255;
        return p;
    };
    float*  x      = (float*)alloc((size_t)NN * HD * 4);
    float*  agg    = (float*)alloc((size_t)NN * HD * 4);
    __half* u      = (__half*)alloc((size_t)NN * HD * 2);
    __half* v      = (__half*)alloc((size_t)NN * HD * 2);
    int*    cnt    = (int*)alloc((size_t)NKEY * 4);
    int*    ofs    = (int*)alloc((size_t)NKEY * 4);
    int*    cursor = (int*)alloc((size_t)NKEY * 4);
    int*    bsum   = (int*)alloc((size_t)1024 * 4);
    int*    bofs   = (int*)alloc((size_t)1024 * 4);
    int2*   em_val = (int2*)alloc((size_t)NE * 8);
    int*    ec_val = (int*)alloc((size_t)NE * 4);
    (void)ws_size; (void)in_sizes; (void)n_in; (void)out_size;

    const int gb_nodes = (NN + 63) / 64;        // 782
    const int gb_edges = (NE + 255) / 256;      // 3125
    const int gb_nwave = (NN * 64 + 255) / 256; // 12500
    const int gb_keys  = NKEY / 256;            // 977

    // ---- CSR build ----
    hipMemsetAsync(cnt, 0, (size_t)NKEY * 4, stream);
    count_kernel<<<gb_edges, 256, 0, stream>>>(ei, cnt);
    scan_blk<<<gb_keys, 256, 0, stream>>>(cnt, bsum);
    scan_top<<<1, 1024, 0, stream>>>(bsum, bofs, gb_keys);
    scan_fin<<<gb_keys, 256, 0, stream>>>(cnt, bofs, ofs);
    hipMemcpyAsync(cursor, ofs, (size_t)NKEY * 4, hipMemcpyDeviceToDevice, stream);
    fill_kernel<<<gb_edges, 256, 0, stream>>>(ei, ef, cursor, em_val, ec_val);

    // ---- network ----
    lin_kernel<10, false><<<gb_nodes, 256, 0, stream>>>(x_in, nullptr, lw[0], lb[0], x);

    for (int i = 0; i < 3; ++i) {
        const float* Wi = em_w + (size_t)i * 129 * HD;
        const float* bi = em_b + (size_t)i * HD;
        for (int o = 0; o < 4; ++o) {
            if (o == 0)
                uv_kernel<false><<<gb_nodes, 256, 0, stream>>>(x, nullptr, nullptr, Wi, bi, u, v);
            else
                uv_kernel<true><<<gb_nodes, 256, 0, stream>>>(x, agg, x, Wi, bi, u, v);
            em_edge<<<gb_nwave, 256, 0, stream>>>(em_val, ofs, u, v, Wi + 128 * HD, agg, o);
        }
        if (i < 2)
            lin_kernel<64, true><<<gb_nodes, 256, 0, stream>>>(x, agg, lw[i + 1], lb[i + 1], x);
    }

    for (int j = 0; j < 3; ++j) {
        const float* Wj = ec_w + (size_t)j * 128 * HD;
        const float* bj = ec_b + (size_t)j * HD;
        if (j == 0)
            uv_kernel<true><<<gb_nodes, 256, 0, stream>>>(x, agg, x, Wj, bj, u, v);
        else
            uv_kernel<false><<<gb_nodes, 256, 0, stream>>>(x, nullptr, nullptr, Wj, bj, u, v);
        ec_edge<<<gb_nwave, 256, 0, stream>>>(ec_val, ofs, u, v, x);
    }

    out_kernel<<<(NN + 255) / 256, 256, 0, stream>>>(x, ow, ob, out);
}

// Round 3
// 1104.119 us; speedup vs baseline: 1.4305x; 1.2490x over previous
//
#include <hip/hip_runtime.h>
#include <hip/hip_fp16.h>

// GraphNN_KNN: N=50000 nodes, E=800000 edges, H=64.
// msg = relu([x_i, x_j-x_i, ef] @ W + b) == relu(u[dst] + v[src] + ef*we)
// with u = x@(Wt-Wm)+b, v = x@Wm. Node GEMMs dense fp32; edge passes gather
// fp16 u/v rows via exact CSR lists. CSR fill uses ranks captured during the
// count pass (no atomics in fill); em payload packed to 4B = dst<<16 | fp16(ef).
// Edge loops are 4-way unrolled for gather ILP (latency-bound otherwise).

#define NN 50000
#define NE 800000
#define PER 200000      // E / 4 orders
#define HD 64
#define NKEY 250112     // 4*NN em keys + NN ec keys, padded to 977*256

// ---------------- CSR build ----------------
// count + per-edge rank capture (rank = atomicAdd return; deg << 256)
__global__ __launch_bounds__(256) void count_kernel(
        const int* __restrict__ ei, int* __restrict__ cnt,
        uchar2* __restrict__ rank) {
    int e = blockIdx.x * 256 + threadIdx.x;
    if (e >= NE) return;
    int src = ei[e];
    int dst = ei[NE + e];
    int o = e / PER;
    int r1 = atomicAdd(&cnt[o * NN + src], 1);
    int r2 = atomicAdd(&cnt[4 * NN + dst], 1);
    rank[e] = make_uchar2((unsigned char)r1, (unsigned char)r2);
}

__global__ __launch_bounds__(256) void scan_blk(
        const int* __restrict__ cnt, int* __restrict__ bsum) {
    __shared__ int s[256];
    int t = threadIdx.x;
    int i = blockIdx.x * 256 + t;
    int c = (i < NKEY) ? cnt[i] : 0;
    s[t] = c; __syncthreads();
    for (int d = 1; d < 256; d <<= 1) {
        int v = (t >= d) ? s[t - d] : 0;
        __syncthreads(); s[t] += v; __syncthreads();
    }
    if (t == 255) bsum[blockIdx.x] = s[255];
}

__global__ __launch_bounds__(1024) void scan_top(
        const int* __restrict__ bsum, int* __restrict__ bofs, int nb) {
    __shared__ int s[1024];
    int t = threadIdx.x;
    int c = (t < nb) ? bsum[t] : 0;
    s[t] = c; __syncthreads();
    for (int d = 1; d < 1024; d <<= 1) {
        int v = (t >= d) ? s[t - d] : 0;
        __syncthreads(); s[t] += v; __syncthreads();
    }
    if (t < nb) bofs[t] = s[t] - c;  // exclusive
}

__global__ __launch_bounds__(256) void scan_fin(
        const int* __restrict__ cnt, const int* __restrict__ bofs,
        int* __restrict__ ofs) {
    __shared__ int s[256];
    int t = threadIdx.x;
    int i = blockIdx.x * 256 + t;
    int c = (i < NKEY) ? cnt[i] : 0;
    s[t] = c; __syncthreads();
    for (int d = 1; d < 256; d <<= 1) {
        int v = (t >= d) ? s[t - d] : 0;
        __syncthreads(); s[t] += v; __syncthreads();
    }
    if (i < NKEY) ofs[i] = bofs[blockIdx.x] + s[t] - c;  // exclusive
}

// fill (no atomics): em value = dst<<16 | fp16(ef) bits; ec value = src
__global__ __launch_bounds__(256) void fill_kernel(
        const int* __restrict__ ei, const float* __restrict__ ef,
        const int* __restrict__ ofs, const uchar2* __restrict__ rank,
        unsigned* __restrict__ em_val, int* __restrict__ ec_val) {
    int e = blockIdx.x * 256 + threadIdx.x;
    if (e >= NE) return;
    int src = ei[e];
    int dst = ei[NE + e];
    int o = e / PER;
    uchar2 r = rank[e];
    int p1 = ofs[o * NN + src] + r.x;
    unsigned short eb = __half_as_ushort(__float2half_rn(ef[e]));
    em_val[p1] = ((unsigned)dst << 16) | (unsigned)eb;
    int p2 = ofs[4 * NN + dst] + r.y - NE;
    ec_val[p2] = src;
}

// ---------------- linear: x = relu((fold? (x+agg)/2 : x) @ W + b) ----------
template<int K, bool FOLD>
__global__ __launch_bounds__(256) void lin_kernel(
        const float* __restrict__ xin, const float* __restrict__ agg,
        const float* __restrict__ W, const float* __restrict__ bias,
        float* __restrict__ xout) {
    __shared__ float xs[64][K + 1];
    int t = threadIdx.x;
    int n0 = blockIdx.x * 64;
    for (int idx = t; idx < 64 * K; idx += 256) {
        int n = idx / K, k = idx - n * K;
        int g = n0 + n;
        float xv = 0.f;
        if (g < NN) {
            xv = xin[(size_t)g * K + k];
            if (FOLD) xv = (xv + agg[(size_t)g * HD + k]) * 0.5f;
        }
        xs[n][k] = xv;
    }
    __syncthreads();
    int ng = t >> 4;
    int f0 = (t & 15) * 4;
    float acc[4][4] = {};
    for (int k = 0; k < K; ++k) {
        float4 w4 = *(const float4*)&W[k * HD + f0];
        #pragma unroll
        for (int j = 0; j < 4; ++j) {
            float xv = xs[ng * 4 + j][k];
            acc[j][0] += xv * w4.x; acc[j][1] += xv * w4.y;
            acc[j][2] += xv * w4.z; acc[j][3] += xv * w4.w;
        }
    }
    float4 b4 = *(const float4*)&bias[f0];
    #pragma unroll
    for (int j = 0; j < 4; ++j) {
        int g = n0 + ng * 4 + j;
        if (g < NN) {
            float4 o;
            o.x = fmaxf(acc[j][0] + b4.x, 0.f);
            o.y = fmaxf(acc[j][1] + b4.y, 0.f);
            o.z = fmaxf(acc[j][2] + b4.z, 0.f);
            o.w = fmaxf(acc[j][3] + b4.w, 0.f);
            *(float4*)&xout[(size_t)g * HD + f0] = o;
        }
    }
}

// ---------------- u/v precompute (fp16 outputs) ----------------------------
template<bool FOLD>
__global__ __launch_bounds__(256) void uv_kernel(
        const float* __restrict__ xin, const float* __restrict__ agg,
        float* __restrict__ xw,
        const float* __restrict__ W, const float* __restrict__ bias,
        __half* __restrict__ u, __half* __restrict__ v) {
    __shared__ float xs[64][65];
    int t = threadIdx.x;
    int n0 = blockIdx.x * 64;
    for (int idx = t; idx < 64 * 64; idx += 256) {
        int n = idx >> 6, k = idx & 63;
        int g = n0 + n;
        float xv = 0.f;
        if (g < NN) {
            xv = xin[(size_t)g * HD + k];
            if (FOLD) {
                xv = (xv + agg[(size_t)g * HD + k]) * 0.5f;
                xw[(size_t)g * HD + k] = xv;
            }
        }
        xs[n][k] = xv;
    }
    __syncthreads();
    int ng = t >> 4;
    int f0 = (t & 15) * 4;
    float acca[4][4] = {};
    float accv[4][4] = {};
    for (int k = 0; k < 64; ++k) {
        float4 wt = *(const float4*)&W[k * HD + f0];
        float4 wm = *(const float4*)&W[(64 + k) * HD + f0];
        #pragma unroll
        for (int j = 0; j < 4; ++j) {
            float xv = xs[ng * 4 + j][k];
            acca[j][0] += xv * wt.x; acca[j][1] += xv * wt.y;
            acca[j][2] += xv * wt.z; acca[j][3] += xv * wt.w;
            accv[j][0] += xv * wm.x; accv[j][1] += xv * wm.y;
            accv[j][2] += xv * wm.z; accv[j][3] += xv * wm.w;
        }
    }
    float4 b4 = *(const float4*)&bias[f0];
    #pragma unroll
    for (int j = 0; j < 4; ++j) {
        int g = n0 + ng * 4 + j;
        if (g < NN) {
            ushort4 uo, vo;
            uo.x = __half_as_ushort(__float2half_rn(acca[j][0] - accv[j][0] + b4.x));
            uo.y = __half_as_ushort(__float2half_rn(acca[j][1] - accv[j][1] + b4.y));
            uo.z = __half_as_ushort(__float2half_rn(acca[j][2] - accv[j][2] + b4.z));
            uo.w = __half_as_ushort(__float2half_rn(acca[j][3] - accv[j][3] + b4.w));
            vo.x = __half_as_ushort(__float2half_rn(accv[j][0]));
            vo.y = __half_as_ushort(__float2half_rn(accv[j][1]));
            vo.z = __half_as_ushort(__float2half_rn(accv[j][2]));
            vo.w = __half_as_ushort(__float2half_rn(accv[j][3]));
            *(ushort4*)&u[(size_t)g * HD + f0] = uo;
            *(ushort4*)&v[(size_t)g * HD + f0] = vo;
        }
    }
}

// ---------------- emulsion edge pass: agg[n] = sum_e relu(u[dst]+v[n]+ef*we)
// wave=node, lane=feature; 4-way unrolled for gather ILP.
__global__ __launch_bounds__(256) void em_edge(
        const unsigned* __restrict__ em_val, const int* __restrict__ ofs,
        const __half* __restrict__ u, const __half* __restrict__ v,
        const float* __restrict__ we, float* __restrict__ agg, int order) {
    int wid = (blockIdx.x * 256 + threadIdx.x) >> 6;
    int lane = threadIdx.x & 63;
    if (wid >= NN) return;
    int key = order * NN + wid;
    int s0 = ofs[key], s1 = ofs[key + 1];
    float vn = __half2float(v[(size_t)wid * HD + lane]);
    float wef = we[lane];
    float a0 = 0.f, a1 = 0.f, a2 = 0.f, a3 = 0.f;
    int p = s0;
    for (; p + 4 <= s1; p += 4) {
        unsigned e0 = em_val[p], e1 = em_val[p + 1];
        unsigned e2 = em_val[p + 2], e3 = em_val[p + 3];
        float u0 = __half2float(u[(size_t)(e0 >> 16) * HD + lane]);
        float u1 = __half2float(u[(size_t)(e1 >> 16) * HD + lane]);
        float u2 = __half2float(u[(size_t)(e2 >> 16) * HD + lane]);
        float u3 = __half2float(u[(size_t)(e3 >> 16) * HD + lane]);
        a0 += fmaxf(u0 + vn + __half2float(__ushort_as_half((unsigned short)e0)) * wef, 0.f);
        a1 += fmaxf(u1 + vn + __half2float(__ushort_as_half((unsigned short)e1)) * wef, 0.f);
        a2 += fmaxf(u2 + vn + __half2float(__ushort_as_half((unsigned short)e2)) * wef, 0.f);
        a3 += fmaxf(u3 + vn + __half2float(__ushort_as_half((unsigned short)e3)) * wef, 0.f);
    }
    for (; p < s1; ++p) {
        unsigned e0 = em_val[p];
        a0 += fmaxf(__half2float(u[(size_t)(e0 >> 16) * HD + lane]) + vn
                    + __half2float(__ushort_as_half((unsigned short)e0)) * wef, 0.f);
    }
    agg[(size_t)wid * HD + lane] = (a0 + a1) + (a2 + a3);
}

// ---------------- edge conv pass: x[n] = max(0, max_e (u[n]+v[src])) -------
__global__ __launch_bounds__(256) void ec_edge(
        const int* __restrict__ ec_val, const int* __restrict__ ofs,
        const __half* __restrict__ u, const __half* __restrict__ v,
        float* __restrict__ xout) {
    int wid = (blockIdx.x * 256 + threadIdx.x) >> 6;
    int lane = threadIdx.x & 63;
    if (wid >= NN) return;
    int s0 = ofs[4 * NN + wid] - NE, s1 = ofs[4 * NN + wid + 1] - NE;
    float un = __half2float(u[(size_t)wid * HD + lane]);
    float m0 = 0.f, m1 = 0.f, m2 = 0.f, m3 = 0.f;  // empty -> 0; msgs relu'd
    int p = s0;
    for (; p + 4 <= s1; p += 4) {
        int i0 = ec_val[p], i1 = ec_val[p + 1];
        int i2 = ec_val[p + 2], i3 = ec_val[p + 3];
        float v0 = __half2float(v[(size_t)i0 * HD + lane]);
        float v1 = __half2float(v[(size_t)i1 * HD + lane]);
        float v2 = __half2float(v[(size_t)i2 * HD + lane]);
        float v3 = __half2float(v[(size_t)i3 * HD + lane]);
        m0 = fmaxf(m0, un + v0);
        m1 = fmaxf(m1, un + v1);
        m2 = fmaxf(m2, un + v2);
        m3 = fmaxf(m3, un + v3);
    }
    for (; p < s1; ++p) {
        int i0 = ec_val[p];
        m0 = fmaxf(m0, un + __half2float(v[(size_t)i0 * HD + lane]));
    }
    xout[(size_t)wid * HD + lane] = fmaxf(fmaxf(m0, m1), fmaxf(m2, m3));
}

// ---------------- output projection ----------------------------------------
__global__ __launch_bounds__(256) void out_kernel(
        const float* __restrict__ x, const float* __restrict__ W,
        const float* __restrict__ bias, float* __restrict__ out) {
    int n = blockIdx.x * 256 + threadIdx.x;
    if (n >= NN) return;
    float xr[HD];
    #pragma unroll
    for (int k = 0; k < HD; k += 4) {
        float4 t4 = *(const float4*)&x[(size_t)n * HD + k];
        xr[k] = t4.x; xr[k + 1] = t4.y; xr[k + 2] = t4.z; xr[k + 3] = t4.w;
    }
    #pragma unroll
    for (int f = 0; f < 10; ++f) {
        float acc = bias[f];
        #pragma unroll
        for (int k = 0; k < HD; ++k) acc += xr[k] * W[k * 10 + f];
        out[(size_t)n * 10 + f] = acc;
    }
}

extern "C" void kernel_launch(void* const* d_in, const int* in_sizes, int n_in,
                              void* d_out, int out_size, void* d_ws, size_t ws_size,
                              hipStream_t stream) {
    const float* x_in  = (const float*)d_in[0];
    const int*   ei    = (const int*)d_in[1];
    const float* ef    = (const float*)d_in[2];
    const float* lw[3] = {(const float*)d_in[3], (const float*)d_in[5], (const float*)d_in[7]};
    const float* lb[3] = {(const float*)d_in[4], (const float*)d_in[6], (const float*)d_in[8]};
    const float* em_w  = (const float*)d_in[9];
    const float* em_b  = (const float*)d_in[10];
    const float* ec_w  = (const float*)d_in[11];
    const float* ec_b  = (const float*)d_in[12];
    const float* ow    = (const float*)d_in[13];
    const float* ob    = (const float*)d_in[14];
    float* out = (float*)d_out;

    char* wsb = (char*)d_ws;
    size_t off = 0;
    auto alloc = [&](size_t bytes) {
        void* p = wsb + off;
        off = (off + bytes + 255) & ~(size_t)255;
        return p;
    };
    float*    x      = (float*)alloc((size_t)NN * HD * 4);
    float*    agg    = (float*)alloc((size_t)NN * HD * 4);
    __half*   u      = (__half*)alloc((size_t)NN * HD * 2);
    __half*   v      = (__half*)alloc((size_t)NN * HD * 2);
    int*      cnt    = (int*)alloc((size_t)NKEY * 4);
    int*      ofs    = (int*)alloc((size_t)NKEY * 4);
    int*      bsum   = (int*)alloc((size_t)1024 * 4);
    int*      bofs   = (int*)alloc((size_t)1024 * 4);
    uchar2*   rank   = (uchar2*)alloc((size_t)NE * 2);
    unsigned* em_val = (unsigned*)alloc((size_t)NE * 4);
    int*      ec_val = (int*)alloc((size_t)NE * 4);
    (void)ws_size; (void)in_sizes; (void)n_in; (void)out_size;

    const int gb_nodes = (NN + 63) / 64;        // 782
    const int gb_edges = (NE + 255) / 256;      // 3125
    const int gb_nwave = (NN * 64 + 255) / 256; // 12500
    const int gb_keys  = NKEY / 256;            // 977

    // ---- CSR build ----
    hipMemsetAsync(cnt, 0, (size_t)NKEY * 4, stream);
    count_kernel<<<gb_edges, 256, 0, stream>>>(ei, cnt, rank);
    scan_blk<<<gb_keys, 256, 0, stream>>>(cnt, bsum);
    scan_top<<<1, 1024, 0, stream>>>(bsum, bofs, gb_keys);
    scan_fin<<<gb_keys, 256, 0, stream>>>(cnt, bofs, ofs);
    fill_kernel<<<gb_edges, 256, 0, stream>>>(ei, ef, ofs, rank, em_val, ec_val);

    // ---- network ----
    lin_kernel<10, false><<<gb_nodes, 256, 0, stream>>>(x_in, nullptr, lw[0], lb[0], x);

    for (int i = 0; i < 3; ++i) {
        const float* Wi = em_w + (size_t)i * 129 * HD;
        const float* bi = em_b + (size_t)i * HD;
        for (int o = 0; o < 4; ++o) {
            if (o == 0)
                uv_kernel<false><<<gb_nodes, 256, 0, stream>>>(x, nullptr, nullptr, Wi, bi, u, v);
            else
                uv_kernel<true><<<gb_nodes, 256, 0, stream>>>(x, agg, x, Wi, bi, u, v);
            em_edge<<<gb_nwave, 256, 0, stream>>>(em_val, ofs, u, v, Wi + 128 * HD, agg, o);
        }
        if (i < 2)
            lin_kernel<64, true><<<gb_nodes, 256, 0, stream>>>(x, agg, lw[i + 1], lb[i + 1], x);
    }

    for (int j = 0; j < 3; ++j) {
        const float* Wj = ec_w + (size_t)j * 128 * HD;
        const float* bj = ec_b + (size_t)j * HD;
        if (j == 0)
            uv_kernel<true><<<gb_nodes, 256, 0, stream>>>(x, agg, x, Wj, bj, u, v);
        else
            uv_kernel<false><<<gb_nodes, 256, 0, stream>>>(x, nullptr, nullptr, Wj, bj, u, v);
        ec_edge<<<gb_nwave, 256, 0, stream>>>(ec_val, ofs, u, v, x);
    }

    out_kernel<<<(NN + 255) / 256, 256, 0, stream>>>(x, ow, ob, out);
}

// Round 4
// 969.739 us; speedup vs baseline: 1.6288x; 1.1386x over previous
//
#include <hip/hip_runtime.h>
#include <hip/hip_fp16.h>

// GraphNN_KNN: N=50000 nodes, E=800000 edges, H=64.
// msg = relu([x_i, x_j-x_i, ef] @ W + b) == relu(u[dst] + v[src] + ef*we)
// with u = x@(Wt-Wm)+b, v = x@Wm. Node GEMMs dense fp32; edge passes gather
// fp16 u/v rows via exact CSR lists. Edge passes use 8 nodes/wave (8 lanes x
// 8 fp16 features each): one gather instruction fetches 8 rows' chunks ->
// 4x fewer VMEM instrs, 8 independent edge streams per wave (latency-bound fix).
// (x+agg)/2 is folded into em_edge (aggregation is node-local), so uv/lin
// never touch an agg buffer.

#define NN 50000
#define NE 800000
#define PER 200000      // E / 4 orders
#define HD 64
#define NKEY 250112     // 4*NN em keys + NN ec keys, padded to 977*256

// ---------------- CSR build ----------------
__global__ __launch_bounds__(256) void count_kernel(
        const int* __restrict__ ei, int* __restrict__ cnt,
        uchar2* __restrict__ rank) {
    int e = blockIdx.x * 256 + threadIdx.x;
    if (e >= NE) return;
    int src = ei[e];
    int dst = ei[NE + e];
    int o = e / PER;
    int r1 = atomicAdd(&cnt[o * NN + src], 1);
    int r2 = atomicAdd(&cnt[4 * NN + dst], 1);
    rank[e] = make_uchar2((unsigned char)r1, (unsigned char)r2);
}

__global__ __launch_bounds__(256) void scan_blk(
        const int* __restrict__ cnt, int* __restrict__ bsum) {
    __shared__ int s[256];
    int t = threadIdx.x;
    int i = blockIdx.x * 256 + t;
    int c = (i < NKEY) ? cnt[i] : 0;
    s[t] = c; __syncthreads();
    for (int d = 1; d < 256; d <<= 1) {
        int v = (t >= d) ? s[t - d] : 0;
        __syncthreads(); s[t] += v; __syncthreads();
    }
    if (t == 255) bsum[blockIdx.x] = s[255];
}

__global__ __launch_bounds__(1024) void scan_top(
        const int* __restrict__ bsum, int* __restrict__ bofs, int nb) {
    __shared__ int s[1024];
    int t = threadIdx.x;
    int c = (t < nb) ? bsum[t] : 0;
    s[t] = c; __syncthreads();
    for (int d = 1; d < 1024; d <<= 1) {
        int v = (t >= d) ? s[t - d] : 0;
        __syncthreads(); s[t] += v; __syncthreads();
    }
    if (t < nb) bofs[t] = s[t] - c;  // exclusive
}

__global__ __launch_bounds__(256) void scan_fin(
        const int* __restrict__ cnt, const int* __restrict__ bofs,
        int* __restrict__ ofs) {
    __shared__ int s[256];
    int t = threadIdx.x;
    int i = blockIdx.x * 256 + t;
    int c = (i < NKEY) ? cnt[i] : 0;
    s[t] = c; __syncthreads();
    for (int d = 1; d < 256; d <<= 1) {
        int v = (t >= d) ? s[t - d] : 0;
        __syncthreads(); s[t] += v; __syncthreads();
    }
    if (i < NKEY) ofs[i] = bofs[blockIdx.x] + s[t] - c;  // exclusive
}

// fill (no atomics): em value = dst<<16 | fp16(ef) bits; ec value = src
__global__ __launch_bounds__(256) void fill_kernel(
        const int* __restrict__ ei, const float* __restrict__ ef,
        const int* __restrict__ ofs, const uchar2* __restrict__ rank,
        unsigned* __restrict__ em_val, int* __restrict__ ec_val) {
    int e = blockIdx.x * 256 + threadIdx.x;
    if (e >= NE) return;
    int src = ei[e];
    int dst = ei[NE + e];
    int o = e / PER;
    uchar2 r = rank[e];
    int p1 = ofs[o * NN + src] + r.x;
    unsigned short eb = __half_as_ushort(__float2half_rn(ef[e]));
    em_val[p1] = ((unsigned)dst << 16) | (unsigned)eb;
    int p2 = ofs[4 * NN + dst] + r.y - NE;
    ec_val[p2] = src;
}

// ---------------- linear: x = relu(x @ W + b) ------------------------------
template<int K>
__global__ __launch_bounds__(256) void lin_kernel(
        const float* __restrict__ xin,
        const float* __restrict__ W, const float* __restrict__ bias,
        float* __restrict__ xout) {
    __shared__ float xs[64][K + 1];
    int t = threadIdx.x;
    int n0 = blockIdx.x * 64;
    for (int idx = t; idx < 64 * K; idx += 256) {
        int n = idx / K, k = idx - n * K;
        int g = n0 + n;
        xs[n][k] = (g < NN) ? xin[(size_t)g * K + k] : 0.f;
    }
    __syncthreads();
    int ng = t >> 4;
    int f0 = (t & 15) * 4;
    float acc[4][4] = {};
    for (int k = 0; k < K; ++k) {
        float4 w4 = *(const float4*)&W[k * HD + f0];
        #pragma unroll
        for (int j = 0; j < 4; ++j) {
            float xv = xs[ng * 4 + j][k];
            acc[j][0] += xv * w4.x; acc[j][1] += xv * w4.y;
            acc[j][2] += xv * w4.z; acc[j][3] += xv * w4.w;
        }
    }
    float4 b4 = *(const float4*)&bias[f0];
    #pragma unroll
    for (int j = 0; j < 4; ++j) {
        int g = n0 + ng * 4 + j;
        if (g < NN) {
            float4 o;
            o.x = fmaxf(acc[j][0] + b4.x, 0.f);
            o.y = fmaxf(acc[j][1] + b4.y, 0.f);
            o.z = fmaxf(acc[j][2] + b4.z, 0.f);
            o.w = fmaxf(acc[j][3] + b4.w, 0.f);
            *(float4*)&xout[(size_t)g * HD + f0] = o;
        }
    }
}

// ---------------- u/v precompute (fp16 outputs) ----------------------------
__global__ __launch_bounds__(256) void uv_kernel(
        const float* __restrict__ xin,
        const float* __restrict__ W, const float* __restrict__ bias,
        __half* __restrict__ u, __half* __restrict__ v) {
    __shared__ float xs[64][65];
    int t = threadIdx.x;
    int n0 = blockIdx.x * 64;
    for (int idx = t; idx < 64 * 64; idx += 256) {
        int n = idx >> 6, k = idx & 63;
        int g = n0 + n;
        xs[n][k] = (g < NN) ? xin[(size_t)g * HD + k] : 0.f;
    }
    __syncthreads();
    int ng = t >> 4;
    int f0 = (t & 15) * 4;
    float acca[4][4] = {};
    float accv[4][4] = {};
    for (int k = 0; k < 64; ++k) {
        float4 wt = *(const float4*)&W[k * HD + f0];
        float4 wm = *(const float4*)&W[(64 + k) * HD + f0];
        #pragma unroll
        for (int j = 0; j < 4; ++j) {
            float xv = xs[ng * 4 + j][k];
            acca[j][0] += xv * wt.x; acca[j][1] += xv * wt.y;
            acca[j][2] += xv * wt.z; acca[j][3] += xv * wt.w;
            accv[j][0] += xv * wm.x; accv[j][1] += xv * wm.y;
            accv[j][2] += xv * wm.z; accv[j][3] += xv * wm.w;
        }
    }
    float4 b4 = *(const float4*)&bias[f0];
    #pragma unroll
    for (int j = 0; j < 4; ++j) {
        int g = n0 + ng * 4 + j;
        if (g < NN) {
            ushort4 uo, vo;
            uo.x = __half_as_ushort(__float2half_rn(acca[j][0] - accv[j][0] + b4.x));
            uo.y = __half_as_ushort(__float2half_rn(acca[j][1] - accv[j][1] + b4.y));
            uo.z = __half_as_ushort(__float2half_rn(acca[j][2] - accv[j][2] + b4.z));
            uo.w = __half_as_ushort(__float2half_rn(acca[j][3] - accv[j][3] + b4.w));
            vo.x = __half_as_ushort(__float2half_rn(accv[j][0]));
            vo.y = __half_as_ushort(__float2half_rn(accv[j][1]));
            vo.z = __half_as_ushort(__float2half_rn(accv[j][2]));
            vo.w = __half_as_ushort(__float2half_rn(accv[j][3]));
            *(ushort4*)&u[(size_t)g * HD + f0] = uo;
            *(ushort4*)&v[(size_t)g * HD + f0] = vo;
        }
    }
}

// load 8 consecutive halves (16B aligned) -> 8 floats
__device__ __forceinline__ void load_h8(const __half* p, float* o) {
    float4 r = *(const float4*)p;
    __half2 h0 = *reinterpret_cast<__half2*>(&r.x);
    __half2 h1 = *reinterpret_cast<__half2*>(&r.y);
    __half2 h2 = *reinterpret_cast<__half2*>(&r.z);
    __half2 h3 = *reinterpret_cast<__half2*>(&r.w);
    float2 f0 = __half22float2(h0), f1 = __half22float2(h1);
    float2 f2 = __half22float2(h2), f3 = __half22float2(h3);
    o[0] = f0.x; o[1] = f0.y; o[2] = f1.x; o[3] = f1.y;
    o[4] = f2.x; o[5] = f2.y; o[6] = f3.x; o[7] = f3.y;
}

// ---------------- emulsion edge pass + fold --------------------------------
// 8 nodes/wave, 8 lanes/node, 8 features/lane.
// x[n] = (x[n] + sum_e relu(u[dst]+v[n]+ef*we)) / 2   (node-local update)
__global__ __launch_bounds__(256) void em_edge(
        const unsigned* __restrict__ em_val, const int* __restrict__ ofs,
        const __half* __restrict__ u, const __half* __restrict__ v,
        const float* __restrict__ we, float* __restrict__ x, int order) {
    int t = threadIdx.x;
    int node = blockIdx.x * 32 + (t >> 3);
    if (node >= NN) return;
    int f0 = (t & 7) * 8;
    int key = order * NN + node;
    int s0 = ofs[key], s1 = ofs[key + 1];
    float vn[8], wef[8], acc[8] = {};
    load_h8(&v[(size_t)node * HD + f0], vn);
    *(float4*)&wef[0] = *(const float4*)&we[f0];
    *(float4*)&wef[4] = *(const float4*)&we[f0 + 4];
    int p = s0;
    for (; p + 2 <= s1; p += 2) {
        unsigned e0 = em_val[p], e1 = em_val[p + 1];
        float u0[8], u1[8];
        load_h8(&u[(size_t)(e0 >> 16) * HD + f0], u0);
        load_h8(&u[(size_t)(e1 >> 16) * HD + f0], u1);
        float ef0 = __half2float(__ushort_as_half((unsigned short)(e0 & 0xffff)));
        float ef1 = __half2float(__ushort_as_half((unsigned short)(e1 & 0xffff)));
        #pragma unroll
        for (int j = 0; j < 8; ++j) {
            acc[j] += fmaxf(u0[j] + vn[j] + ef0 * wef[j], 0.f)
                    + fmaxf(u1[j] + vn[j] + ef1 * wef[j], 0.f);
        }
    }
    if (p < s1) {
        unsigned e0 = em_val[p];
        float u0[8];
        load_h8(&u[(size_t)(e0 >> 16) * HD + f0], u0);
        float ef0 = __half2float(__ushort_as_half((unsigned short)(e0 & 0xffff)));
        #pragma unroll
        for (int j = 0; j < 8; ++j)
            acc[j] += fmaxf(u0[j] + vn[j] + ef0 * wef[j], 0.f);
    }
    float xr[8];
    *(float4*)&xr[0] = *(const float4*)&x[(size_t)node * HD + f0];
    *(float4*)&xr[4] = *(const float4*)&x[(size_t)node * HD + f0 + 4];
    #pragma unroll
    for (int j = 0; j < 8; ++j) xr[j] = (xr[j] + acc[j]) * 0.5f;
    *(float4*)&x[(size_t)node * HD + f0] = *(float4*)&xr[0];
    *(float4*)&x[(size_t)node * HD + f0 + 4] = *(float4*)&xr[4];
}

// ---------------- edge conv pass: x[n] = max(0, max_e (u[n]+v[src])) -------
__global__ __launch_bounds__(256) void ec_edge(
        const int* __restrict__ ec_val, const int* __restrict__ ofs,
        const __half* __restrict__ u, const __half* __restrict__ v,
        float* __restrict__ x) {
    int t = threadIdx.x;
    int node = blockIdx.x * 32 + (t >> 3);
    if (node >= NN) return;
    int f0 = (t & 7) * 8;
    int s0 = ofs[4 * NN + node] - NE, s1 = ofs[4 * NN + node + 1] - NE;
    float un[8], m[8] = {};  // init 0: empty -> 0, and relu'd msgs >= 0
    load_h8(&u[(size_t)node * HD + f0], un);
    int p = s0;
    for (; p + 2 <= s1; p += 2) {
        int i0 = ec_val[p], i1 = ec_val[p + 1];
        float v0[8], v1[8];
        load_h8(&v[(size_t)i0 * HD + f0], v0);
        load_h8(&v[(size_t)i1 * HD + f0], v1);
        #pragma unroll
        for (int j = 0; j < 8; ++j)
            m[j] = fmaxf(m[j], fmaxf(un[j] + v0[j], un[j] + v1[j]));
    }
    if (p < s1) {
        int i0 = ec_val[p];
        float v0[8];
        load_h8(&v[(size_t)i0 * HD + f0], v0);
        #pragma unroll
        for (int j = 0; j < 8; ++j) m[j] = fmaxf(m[j], un[j] + v0[j]);
    }
    *(float4*)&x[(size_t)node * HD + f0] = *(float4*)&m[0];
    *(float4*)&x[(size_t)node * HD + f0 + 4] = *(float4*)&m[4];
}

// ---------------- output projection ----------------------------------------
__global__ __launch_bounds__(256) void out_kernel(
        const float* __restrict__ x, const float* __restrict__ W,
        const float* __restrict__ bias, float* __restrict__ out) {
    int n = blockIdx.x * 256 + threadIdx.x;
    if (n >= NN) return;
    float xr[HD];
    #pragma unroll
    for (int k = 0; k < HD; k += 4) {
        float4 t4 = *(const float4*)&x[(size_t)n * HD + k];
        xr[k] = t4.x; xr[k + 1] = t4.y; xr[k + 2] = t4.z; xr[k + 3] = t4.w;
    }
    #pragma unroll
    for (int f = 0; f < 10; ++f) {
        float acc = bias[f];
        #pragma unroll
        for (int k = 0; k < HD; ++k) acc += xr[k] * W[k * 10 + f];
        out[(size_t)n * 10 + f] = acc;
    }
}

extern "C" void kernel_launch(void* const* d_in, const int* in_sizes, int n_in,
                              void* d_out, int out_size, void* d_ws, size_t ws_size,
                              hipStream_t stream) {
    const float* x_in  = (const float*)d_in[0];
    const int*   ei    = (const int*)d_in[1];
    const float* ef    = (const float*)d_in[2];
    const float* lw[3] = {(const float*)d_in[3], (const float*)d_in[5], (const float*)d_in[7]};
    const float* lb[3] = {(const float*)d_in[4], (const float*)d_in[6], (const float*)d_in[8]};
    const float* em_w  = (const float*)d_in[9];
    const float* em_b  = (const float*)d_in[10];
    const float* ec_w  = (const float*)d_in[11];
    const float* ec_b  = (const float*)d_in[12];
    const float* ow    = (const float*)d_in[13];
    const float* ob    = (const float*)d_in[14];
    float* out = (float*)d_out;

    char* wsb = (char*)d_ws;
    size_t off = 0;
    auto alloc = [&](size_t bytes) {
        void* p = wsb + off;
        off = (off + bytes + 255) & ~(size_t)255;
        return p;
    };
    float*    x      = (float*)alloc((size_t)NN * HD * 4);
    __half*   u      = (__half*)alloc((size_t)NN * HD * 2);
    __half*   v      = (__half*)alloc((size_t)NN * HD * 2);
    int*      cnt    = (int*)alloc((size_t)NKEY * 4);
    int*      ofs    = (int*)alloc((size_t)NKEY * 4);
    int*      bsum   = (int*)alloc((size_t)1024 * 4);
    int*      bofs   = (int*)alloc((size_t)1024 * 4);
    uchar2*   rank   = (uchar2*)alloc((size_t)NE * 2);
    unsigned* em_val = (unsigned*)alloc((size_t)NE * 4);
    int*      ec_val = (int*)alloc((size_t)NE * 4);
    (void)ws_size; (void)in_sizes; (void)n_in; (void)out_size;

    const int gb_nodes = (NN + 63) / 64;   // 782
    const int gb_edges = (NE + 255) / 256; // 3125
    const int gb_n8    = (NN + 31) / 32;   // 1563 (32 nodes per 256-thr block)
    const int gb_keys  = NKEY / 256;       // 977

    // ---- CSR build ----
    hipMemsetAsync(cnt, 0, (size_t)NKEY * 4, stream);
    count_kernel<<<gb_edges, 256, 0, stream>>>(ei, cnt, rank);
    scan_blk<<<gb_keys, 256, 0, stream>>>(cnt, bsum);
    scan_top<<<1, 1024, 0, stream>>>(bsum, bofs, gb_keys);
    scan_fin<<<gb_keys, 256, 0, stream>>>(cnt, bofs, ofs);
    fill_kernel<<<gb_edges, 256, 0, stream>>>(ei, ef, ofs, rank, em_val, ec_val);

    // ---- network ----
    lin_kernel<10><<<gb_nodes, 256, 0, stream>>>(x_in, lw[0], lb[0], x);

    for (int i = 0; i < 3; ++i) {
        const float* Wi = em_w + (size_t)i * 129 * HD;
        const float* bi = em_b + (size_t)i * HD;
        for (int o = 0; o < 4; ++o) {
            uv_kernel<<<gb_nodes, 256, 0, stream>>>(x, Wi, bi, u, v);
            em_edge<<<gb_n8, 256, 0, stream>>>(em_val, ofs, u, v, Wi + 128 * HD, x, o);
        }
        if (i < 2)
            lin_kernel<64><<<gb_nodes, 256, 0, stream>>>(x, lw[i + 1], lb[i + 1], x);
    }

    for (int j = 0; j < 3; ++j) {
        const float* Wj = ec_w + (size_t)j * 128 * HD;
        const float* bj = ec_b + (size_t)j * HD;
        uv_kernel<<<gb_nodes, 256, 0, stream>>>(x, Wj, bj, u, v);
        ec_edge<<<gb_n8, 256, 0, stream>>>(ec_val, ofs, u, v, x);
    }

    out_kernel<<<(NN + 255) / 256, 256, 0, stream>>>(x, ow, ob, out);
}

// Round 5
// 579.224 us; speedup vs baseline: 2.7269x; 1.6742x over previous
//
#include <hip/hip_runtime.h>
#include <hip/hip_fp16.h>

// GraphNN_KNN: N=50000 nodes, E=800000 edges, H=64.
// msg = relu([x_i, x_j-x_i, ef] @ W + b) == relu(u[dst] + v[src] + ef*we)
// with u = x@(Wt-Wm)+b, v = x@Wm. u/v GEMMs now use MFMA 16x16x32_f16 with
// split-fp16 inputs (x=xh+xl, W=Wh+Wl; 3 product terms) to keep fp32-level
// accuracy; outputs stored fp16 for the gather passes. Edge passes: 8 nodes/
// wave, 8 lanes/node, 16B fp16 gathers. CSR built per launch (count w/ rank
// capture -> scan -> atomic-free fill).

#define NN 50000
#define NE 800000
#define PER 200000      // E / 4 orders
#define HD 64
#define NKEY 250112     // 4*NN em keys + NN ec keys, padded to 977*256

typedef _Float16 half8 __attribute__((ext_vector_type(8)));
typedef float float4v __attribute__((ext_vector_type(4)));

// ---------------- CSR build ----------------
__global__ __launch_bounds__(256) void count_kernel(
        const int* __restrict__ ei, int* __restrict__ cnt,
        uchar2* __restrict__ rank) {
    int e = blockIdx.x * 256 + threadIdx.x;
    if (e >= NE) return;
    int src = ei[e];
    int dst = ei[NE + e];
    int o = e / PER;
    int r1 = atomicAdd(&cnt[o * NN + src], 1);
    int r2 = atomicAdd(&cnt[4 * NN + dst], 1);
    rank[e] = make_uchar2((unsigned char)r1, (unsigned char)r2);
}

__global__ __launch_bounds__(256) void scan_blk(
        const int* __restrict__ cnt, int* __restrict__ bsum) {
    __shared__ int s[256];
    int t = threadIdx.x;
    int i = blockIdx.x * 256 + t;
    int c = (i < NKEY) ? cnt[i] : 0;
    s[t] = c; __syncthreads();
    for (int d = 1; d < 256; d <<= 1) {
        int v = (t >= d) ? s[t - d] : 0;
        __syncthreads(); s[t] += v; __syncthreads();
    }
    if (t == 255) bsum[blockIdx.x] = s[255];
}

__global__ __launch_bounds__(1024) void scan_top(
        const int* __restrict__ bsum, int* __restrict__ bofs, int nb) {
    __shared__ int s[1024];
    int t = threadIdx.x;
    int c = (t < nb) ? bsum[t] : 0;
    s[t] = c; __syncthreads();
    for (int d = 1; d < 1024; d <<= 1) {
        int v = (t >= d) ? s[t - d] : 0;
        __syncthreads(); s[t] += v; __syncthreads();
    }
    if (t < nb) bofs[t] = s[t] - c;  // exclusive
}

__global__ __launch_bounds__(256) void scan_fin(
        const int* __restrict__ cnt, const int* __restrict__ bofs,
        int* __restrict__ ofs) {
    __shared__ int s[256];
    int t = threadIdx.x;
    int i = blockIdx.x * 256 + t;
    int c = (i < NKEY) ? cnt[i] : 0;
    s[t] = c; __syncthreads();
    for (int d = 1; d < 256; d <<= 1) {
        int v = (t >= d) ? s[t - d] : 0;
        __syncthreads(); s[t] += v; __syncthreads();
    }
    if (i < NKEY) ofs[i] = bofs[blockIdx.x] + s[t] - c;  // exclusive
}

// fill (no atomics): em value = dst<<16 | fp16(ef) bits; ec value = src
__global__ __launch_bounds__(256) void fill_kernel(
        const int* __restrict__ ei, const float* __restrict__ ef,
        const int* __restrict__ ofs, const uchar2* __restrict__ rank,
        unsigned* __restrict__ em_val, int* __restrict__ ec_val) {
    int e = blockIdx.x * 256 + threadIdx.x;
    if (e >= NE) return;
    int src = ei[e];
    int dst = ei[NE + e];
    int o = e / PER;
    uchar2 r = rank[e];
    int p1 = ofs[o * NN + src] + r.x;
    unsigned short eb = __half_as_ushort(__float2half_rn(ef[e]));
    em_val[p1] = ((unsigned)dst << 16) | (unsigned)eb;
    int p2 = ofs[4 * NN + dst] + r.y - NE;
    ec_val[p2] = src;
}

// ---------------- weight prep: split-fp16, transposed [n][k] ---------------
// mats 0-2 emWu, 3-5 emWv, 6-8 ecWu, 9-11 ecWv; lo parts at +12 mats.
__global__ __launch_bounds__(256) void prep_w(
        const float* __restrict__ em_w, const float* __restrict__ ec_w,
        _Float16* __restrict__ wh) {
    int idx = blockIdx.x * 256 + threadIdx.x;   // < 12*4096
    int mat = idx >> 12, pos = idx & 4095;
    int n = pos >> 6, k = pos & 63;
    float val;
    if (mat < 3)      { const float* B = em_w + mat * 129 * 64;     val = B[k*64+n] - B[(64+k)*64+n]; }
    else if (mat < 6) { const float* B = em_w + (mat-3) * 129 * 64; val = B[(64+k)*64+n]; }
    else if (mat < 9) { const float* B = ec_w + (mat-6) * 128 * 64; val = B[k*64+n] - B[(64+k)*64+n]; }
    else              { const float* B = ec_w + (mat-9) * 128 * 64; val = B[(64+k)*64+n]; }
    _Float16 h = (_Float16)val;
    _Float16 l = (_Float16)(val - (float)h);
    wh[(size_t)mat * 4096 + n * 64 + k] = h;
    wh[(size_t)(12 + mat) * 4096 + n * 64 + k] = l;
}

// ---------------- linear: x = relu(x @ W + b), scalar fp32 ------------------
template<int K>
__global__ __launch_bounds__(256) void lin_kernel(
        const float* __restrict__ xin,
        const float* __restrict__ W, const float* __restrict__ bias,
        float* __restrict__ xout) {
    __shared__ float xs[64][K + 1];
    int t = threadIdx.x;
    int n0 = blockIdx.x * 64;
    for (int idx = t; idx < 64 * K; idx += 256) {
        int n = idx / K, k = idx - n * K;
        int g = n0 + n;
        xs[n][k] = (g < NN) ? xin[(size_t)g * K + k] : 0.f;
    }
    __syncthreads();
    int ng = t >> 4;
    int f0 = (t & 15) * 4;
    float acc[4][4] = {};
    for (int k = 0; k < K; ++k) {
        float4 w4 = *(const float4*)&W[k * HD + f0];
        #pragma unroll
        for (int j = 0; j < 4; ++j) {
            float xv = xs[ng * 4 + j][k];
            acc[j][0] += xv * w4.x; acc[j][1] += xv * w4.y;
            acc[j][2] += xv * w4.z; acc[j][3] += xv * w4.w;
        }
    }
    float4 b4 = *(const float4*)&bias[f0];
    #pragma unroll
    for (int j = 0; j < 4; ++j) {
        int g = n0 + ng * 4 + j;
        if (g < NN) {
            float4 o;
            o.x = fmaxf(acc[j][0] + b4.x, 0.f);
            o.y = fmaxf(acc[j][1] + b4.y, 0.f);
            o.z = fmaxf(acc[j][2] + b4.z, 0.f);
            o.w = fmaxf(acc[j][3] + b4.w, 0.f);
            *(float4*)&xout[(size_t)g * HD + f0] = o;
        }
    }
}

// ---------------- u/v via MFMA, split-fp16 ---------------------------------
// u = x@Wu + b, v = x@Wv.  64 nodes/block, 4 waves, wave w -> node rows w*16..
// A-frag: A[m=lane&15][k=quad*8+j]; B-frag: W^T[n=lane&15][k=quad*8+j];
// C: col(n)=lane&15, row(m)=quad*4+reg.  Split: x=xh+xl, W=Wh+Wl;
// acc = xh*Wh + xl*Wh + xh*Wl  (error ~eps^2, fp16-storage rounding dominates).
__global__ __launch_bounds__(256) void uv_mfma(
        const float* __restrict__ x,
        const _Float16* __restrict__ Wuh, const _Float16* __restrict__ Wul,
        const _Float16* __restrict__ Wvh, const _Float16* __restrict__ Wvl,
        const float* __restrict__ bias,
        _Float16* __restrict__ u, _Float16* __restrict__ v) {
    __shared__ _Float16 xh[64 * 72], xl[64 * 72];
    __shared__ _Float16 wuh[64 * 72], wul[64 * 72];
    __shared__ _Float16 wvh[64 * 72], wvl[64 * 72];
    __shared__ _Float16 rp[4 * 16 * 72];
    int t = threadIdx.x;
    int n0 = blockIdx.x * 64;

    { // stage x (split) : thread t -> node t>>2, 16 k at (t&3)*16
        int node = t >> 2, k0 = (t & 3) * 16;
        int g = n0 + node;
        float f[16];
        if (g < NN) {
            const float4* xr = (const float4*)&x[(size_t)g * HD + k0];
            *(float4*)&f[0] = xr[0]; *(float4*)&f[4] = xr[1];
            *(float4*)&f[8] = xr[2]; *(float4*)&f[12] = xr[3];
        } else {
            #pragma unroll
            for (int j = 0; j < 16; ++j) f[j] = 0.f;
        }
        half8 h0, h1, l0, l1;
        #pragma unroll
        for (int j = 0; j < 8; ++j) {
            _Float16 h = (_Float16)f[j];
            h0[j] = h; l0[j] = (_Float16)(f[j] - (float)h);
            _Float16 g2 = (_Float16)f[j + 8];
            h1[j] = g2; l1[j] = (_Float16)(f[j + 8] - (float)g2);
        }
        *(half8*)&xh[node * 72 + k0] = h0; *(half8*)&xh[node * 72 + k0 + 8] = h1;
        *(half8*)&xl[node * 72 + k0] = l0; *(half8*)&xl[node * 72 + k0 + 8] = l1;
    }
    { // stage W (4 arrays), row remap into 72-padded LDS
        int n = t >> 2, c = (t & 3) * 16;
        *(half8*)&wuh[n * 72 + c]     = *(const half8*)&Wuh[n * 64 + c];
        *(half8*)&wuh[n * 72 + c + 8] = *(const half8*)&Wuh[n * 64 + c + 8];
        *(half8*)&wul[n * 72 + c]     = *(const half8*)&Wul[n * 64 + c];
        *(half8*)&wul[n * 72 + c + 8] = *(const half8*)&Wul[n * 64 + c + 8];
        *(half8*)&wvh[n * 72 + c]     = *(const half8*)&Wvh[n * 64 + c];
        *(half8*)&wvh[n * 72 + c + 8] = *(const half8*)&Wvh[n * 64 + c + 8];
        *(half8*)&wvl[n * 72 + c]     = *(const half8*)&Wvl[n * 64 + c];
        *(half8*)&wvl[n * 72 + c + 8] = *(const half8*)&Wvl[n * 64 + c + 8];
    }
    __syncthreads();

    int w = t >> 6, lane = t & 63;
    int quad = lane >> 4, l16 = lane & 15;
    int m0 = w * 16;
    half8 ah0 = *(half8*)&xh[(m0 + l16) * 72 + quad * 8];
    half8 ah1 = *(half8*)&xh[(m0 + l16) * 72 + 32 + quad * 8];
    half8 al0 = *(half8*)&xl[(m0 + l16) * 72 + quad * 8];
    half8 al1 = *(half8*)&xl[(m0 + l16) * 72 + 32 + quad * 8];

    float4v au[4], av[4];
    #pragma unroll
    for (int nt = 0; nt < 4; ++nt) {
        int n = nt * 16 + l16;
        half8 bh0 = *(half8*)&wuh[n * 72 + quad * 8];
        half8 bh1 = *(half8*)&wuh[n * 72 + 32 + quad * 8];
        half8 bl0 = *(half8*)&wul[n * 72 + quad * 8];
        half8 bl1 = *(half8*)&wul[n * 72 + 32 + quad * 8];
        float4v acc = {0.f, 0.f, 0.f, 0.f};
        acc = __builtin_amdgcn_mfma_f32_16x16x32_f16(ah0, bh0, acc, 0, 0, 0);
        acc = __builtin_amdgcn_mfma_f32_16x16x32_f16(ah1, bh1, acc, 0, 0, 0);
        acc = __builtin_amdgcn_mfma_f32_16x16x32_f16(al0, bh0, acc, 0, 0, 0);
        acc = __builtin_amdgcn_mfma_f32_16x16x32_f16(al1, bh1, acc, 0, 0, 0);
        acc = __builtin_amdgcn_mfma_f32_16x16x32_f16(ah0, bl0, acc, 0, 0, 0);
        acc = __builtin_amdgcn_mfma_f32_16x16x32_f16(ah1, bl1, acc, 0, 0, 0);
        au[nt] = acc;
        half8 ch0 = *(half8*)&wvh[n * 72 + quad * 8];
        half8 ch1 = *(half8*)&wvh[n * 72 + 32 + quad * 8];
        half8 cl0 = *(half8*)&wvl[n * 72 + quad * 8];
        half8 cl1 = *(half8*)&wvl[n * 72 + 32 + quad * 8];
        float4v accv = {0.f, 0.f, 0.f, 0.f};
        accv = __builtin_amdgcn_mfma_f32_16x16x32_f16(ah0, ch0, accv, 0, 0, 0);
        accv = __builtin_amdgcn_mfma_f32_16x16x32_f16(ah1, ch1, accv, 0, 0, 0);
        accv = __builtin_amdgcn_mfma_f32_16x16x32_f16(al0, ch0, accv, 0, 0, 0);
        accv = __builtin_amdgcn_mfma_f32_16x16x32_f16(al1, ch1, accv, 0, 0, 0);
        accv = __builtin_amdgcn_mfma_f32_16x16x32_f16(ah0, cl0, accv, 0, 0, 0);
        accv = __builtin_amdgcn_mfma_f32_16x16x32_f16(ah1, cl1, accv, 0, 0, 0);
        av[nt] = accv;
    }

    // repack u (+bias) through per-wave LDS, store 16B vectors
    _Float16* rpw = &rp[w * 16 * 72];
    #pragma unroll
    for (int nt = 0; nt < 4; ++nt) {
        float bn = bias[nt * 16 + l16];
        #pragma unroll
        for (int r = 0; r < 4; ++r)
            rpw[(quad * 4 + r) * 72 + nt * 16 + l16] = (_Float16)(au[nt][r] + bn);
    }
    int mr = lane >> 2, cr = (lane & 3) * 16;
    int gr = n0 + m0 + mr;
    if (gr < NN) {
        *(half8*)&u[(size_t)gr * HD + cr]     = *(half8*)&rpw[mr * 72 + cr];
        *(half8*)&u[(size_t)gr * HD + cr + 8] = *(half8*)&rpw[mr * 72 + cr + 8];
    }
    // repack v (DS pipe is in-order per wave: prior reads complete first)
    #pragma unroll
    for (int nt = 0; nt < 4; ++nt) {
        #pragma unroll
        for (int r = 0; r < 4; ++r)
            rpw[(quad * 4 + r) * 72 + nt * 16 + l16] = (_Float16)(av[nt][r]);
    }
    if (gr < NN) {
        *(half8*)&v[(size_t)gr * HD + cr]     = *(half8*)&rpw[mr * 72 + cr];
        *(half8*)&v[(size_t)gr * HD + cr + 8] = *(half8*)&rpw[mr * 72 + cr + 8];
    }
}

// load 8 consecutive halves (16B aligned) -> 8 floats
__device__ __forceinline__ void load_h8(const __half* p, float* o) {
    float4 r = *(const float4*)p;
    __half2 h0 = *reinterpret_cast<__half2*>(&r.x);
    __half2 h1 = *reinterpret_cast<__half2*>(&r.y);
    __half2 h2 = *reinterpret_cast<__half2*>(&r.z);
    __half2 h3 = *reinterpret_cast<__half2*>(&r.w);
    float2 f0 = __half22float2(h0), f1 = __half22float2(h1);
    float2 f2 = __half22float2(h2), f3 = __half22float2(h3);
    o[0] = f0.x; o[1] = f0.y; o[2] = f1.x; o[3] = f1.y;
    o[4] = f2.x; o[5] = f2.y; o[6] = f3.x; o[7] = f3.y;
}

// ---------------- emulsion edge pass + fold --------------------------------
// 8 nodes/wave, 8 lanes/node, 8 features/lane.
// x[n] = (x[n] + sum_e relu(u[dst]+v[n]+ef*we)) / 2   (node-local update)
__global__ __launch_bounds__(256) void em_edge(
        const unsigned* __restrict__ em_val, const int* __restrict__ ofs,
        const __half* __restrict__ u, const __half* __restrict__ v,
        const float* __restrict__ we, float* __restrict__ x, int order) {
    int t = threadIdx.x;
    int node = blockIdx.x * 32 + (t >> 3);
    if (node >= NN) return;
    int f0 = (t & 7) * 8;
    int key = order * NN + node;
    int s0 = ofs[key], s1 = ofs[key + 1];
    float vn[8], wef[8], acc[8] = {};
    load_h8(&v[(size_t)node * HD + f0], vn);
    *(float4*)&wef[0] = *(const float4*)&we[f0];
    *(float4*)&wef[4] = *(const float4*)&we[f0 + 4];
    int p = s0;
    for (; p + 2 <= s1; p += 2) {
        unsigned e0 = em_val[p], e1 = em_val[p + 1];
        float u0[8], u1[8];
        load_h8(&u[(size_t)(e0 >> 16) * HD + f0], u0);
        load_h8(&u[(size_t)(e1 >> 16) * HD + f0], u1);
        float ef0 = __half2float(__ushort_as_half((unsigned short)(e0 & 0xffff)));
        float ef1 = __half2float(__ushort_as_half((unsigned short)(e1 & 0xffff)));
        #pragma unroll
        for (int j = 0; j < 8; ++j) {
            acc[j] += fmaxf(u0[j] + vn[j] + ef0 * wef[j], 0.f)
                    + fmaxf(u1[j] + vn[j] + ef1 * wef[j], 0.f);
        }
    }
    if (p < s1) {
        unsigned e0 = em_val[p];
        float u0[8];
        load_h8(&u[(size_t)(e0 >> 16) * HD + f0], u0);
        float ef0 = __half2float(__ushort_as_half((unsigned short)(e0 & 0xffff)));
        #pragma unroll
        for (int j = 0; j < 8; ++j)
            acc[j] += fmaxf(u0[j] + vn[j] + ef0 * wef[j], 0.f);
    }
    float xr[8];
    *(float4*)&xr[0] = *(const float4*)&x[(size_t)node * HD + f0];
    *(float4*)&xr[4] = *(const float4*)&x[(size_t)node * HD + f0 + 4];
    #pragma unroll
    for (int j = 0; j < 8; ++j) xr[j] = (xr[j] + acc[j]) * 0.5f;
    *(float4*)&x[(size_t)node * HD + f0] = *(float4*)&xr[0];
    *(float4*)&x[(size_t)node * HD + f0 + 4] = *(float4*)&xr[4];
}

// ---------------- edge conv pass: x[n] = max(0, max_e (u[n]+v[src])) -------
__global__ __launch_bounds__(256) void ec_edge(
        const int* __restrict__ ec_val, const int* __restrict__ ofs,
        const __half* __restrict__ u, const __half* __restrict__ v,
        float* __restrict__ x) {
    int t = threadIdx.x;
    int node = blockIdx.x * 32 + (t >> 3);
    if (node >= NN) return;
    int f0 = (t & 7) * 8;
    int s0 = ofs[4 * NN + node] - NE, s1 = ofs[4 * NN + node + 1] - NE;
    float un[8], m[8] = {};  // init 0: empty -> 0, and relu'd msgs >= 0
    load_h8(&u[(size_t)node * HD + f0], un);
    int p = s0;
    for (; p + 2 <= s1; p += 2) {
        int i0 = ec_val[p], i1 = ec_val[p + 1];
        float v0[8], v1[8];
        load_h8(&v[(size_t)i0 * HD + f0], v0);
        load_h8(&v[(size_t)i1 * HD + f0], v1);
        #pragma unroll
        for (int j = 0; j < 8; ++j)
            m[j] = fmaxf(m[j], fmaxf(un[j] + v0[j], un[j] + v1[j]));
    }
    if (p < s1) {
        int i0 = ec_val[p];
        float v0[8];
        load_h8(&v[(size_t)i0 * HD + f0], v0);
        #pragma unroll
        for (int j = 0; j < 8; ++j) m[j] = fmaxf(m[j], un[j] + v0[j]);
    }
    *(float4*)&x[(size_t)node * HD + f0] = *(float4*)&m[0];
    *(float4*)&x[(size_t)node * HD + f0 + 4] = *(float4*)&m[4];
}

// ---------------- output projection ----------------------------------------
__global__ __launch_bounds__(256) void out_kernel(
        const float* __restrict__ x, const float* __restrict__ W,
        const float* __restrict__ bias, float* __restrict__ out) {
    int n = blockIdx.x * 256 + threadIdx.x;
    if (n >= NN) return;
    float xr[HD];
    #pragma unroll
    for (int k = 0; k < HD; k += 4) {
        float4 t4 = *(const float4*)&x[(size_t)n * HD + k];
        xr[k] = t4.x; xr[k + 1] = t4.y; xr[k + 2] = t4.z; xr[k + 3] = t4.w;
    }
    #pragma unroll
    for (int f = 0; f < 10; ++f) {
        float acc = bias[f];
        #pragma unroll
        for (int k = 0; k < HD; ++k) acc += xr[k] * W[k * 10 + f];
        out[(size_t)n * 10 + f] = acc;
    }
}

extern "C" void kernel_launch(void* const* d_in, const int* in_sizes, int n_in,
                              void* d_out, int out_size, void* d_ws, size_t ws_size,
                              hipStream_t stream) {
    const float* x_in  = (const float*)d_in[0];
    const int*   ei    = (const int*)d_in[1];
    const float* ef    = (const float*)d_in[2];
    const float* lw[3] = {(const float*)d_in[3], (const float*)d_in[5], (const float*)d_in[7]};
    const float* lb[3] = {(const float*)d_in[4], (const float*)d_in[6], (const float*)d_in[8]};
    const float* em_w  = (const float*)d_in[9];
    const float* em_b  = (const float*)d_in[10];
    const float* ec_w  = (const float*)d_in[11];
    const float* ec_b  = (const float*)d_in[12];
    const float* ow    = (const float*)d_in[13];
    const float* ob    = (const float*)d_in[14];
    float* out = (float*)d_out;

    char* wsb = (char*)d_ws;
    size_t off = 0;
    auto alloc = [&](size_t bytes) {
        void* p = wsb + off;
        off = (off + bytes + 255) & ~(size_t)255;
        return p;
    };
    float*     x      = (float*)alloc((size_t)NN * HD * 4);
    _Float16*  u      = (_Float16*)alloc((size_t)NN * HD * 2);
    _Float16*  v      = (_Float16*)alloc((size_t)NN * HD * 2);
    int*       cnt    = (int*)alloc((size_t)NKEY * 4);
    int*       ofs    = (int*)alloc((size_t)NKEY * 4);
    int*       bsum   = (int*)alloc((size_t)1024 * 4);
    int*       bofs   = (int*)alloc((size_t)1024 * 4);
    uchar2*    rank   = (uchar2*)alloc((size_t)NE * 2);
    unsigned*  em_val = (unsigned*)alloc((size_t)NE * 4);
    int*       ec_val = (int*)alloc((size_t)NE * 4);
    _Float16*  wh     = (_Float16*)alloc((size_t)24 * 4096 * 2);
    (void)ws_size; (void)in_sizes; (void)n_in; (void)out_size;

    const int gb_nodes = (NN + 63) / 64;   // 782
    const int gb_edges = (NE + 255) / 256; // 3125
    const int gb_n8    = (NN + 31) / 32;   // 1563
    const int gb_keys  = NKEY / 256;       // 977

    // ---- CSR build + weight prep ----
    hipMemsetAsync(cnt, 0, (size_t)NKEY * 4, stream);
    count_kernel<<<gb_edges, 256, 0, stream>>>(ei, cnt, rank);
    prep_w<<<192, 256, 0, stream>>>(em_w, ec_w, wh);
    scan_blk<<<gb_keys, 256, 0, stream>>>(cnt, bsum);
    scan_top<<<1, 1024, 0, stream>>>(bsum, bofs, gb_keys);
    scan_fin<<<gb_keys, 256, 0, stream>>>(cnt, bofs, ofs);
    fill_kernel<<<gb_edges, 256, 0, stream>>>(ei, ef, ofs, rank, em_val, ec_val);

    // ---- network ----
    lin_kernel<10><<<gb_nodes, 256, 0, stream>>>(x_in, lw[0], lb[0], x);

    for (int i = 0; i < 3; ++i) {
        const _Float16* Wuh = wh + (size_t)i * 4096;
        const _Float16* Wvh = wh + (size_t)(3 + i) * 4096;
        const _Float16* Wul = wh + (size_t)(12 + i) * 4096;
        const _Float16* Wvl = wh + (size_t)(15 + i) * 4096;
        const float* bi = em_b + (size_t)i * HD;
        const float* we = em_w + (size_t)i * 129 * HD + 128 * HD;
        for (int o = 0; o < 4; ++o) {
            uv_mfma<<<gb_nodes, 256, 0, stream>>>(x, Wuh, Wul, Wvh, Wvl, bi, u, v);
            em_edge<<<gb_n8, 256, 0, stream>>>(em_val, ofs, (const __half*)u,
                                               (const __half*)v, we, x, o);
        }
        if (i < 2)
            lin_kernel<64><<<gb_nodes, 256, 0, stream>>>(x, lw[i + 1], lb[i + 1], x);
    }

    for (int j = 0; j < 3; ++j) {
        const _Float16* Wuh = wh + (size_t)(6 + j) * 4096;
        const _Float16* Wvh = wh + (size_t)(9 + j) * 4096;
        const _Float16* Wul = wh + (size_t)(18 + j) * 4096;
        const _Float16* Wvl = wh + (size_t)(21 + j) * 4096;
        const float* bj = ec_b + (size_t)j * HD;
        uv_mfma<<<gb_nodes, 256, 0, stream>>>(x, Wuh, Wul, Wvh, Wvl, bj, u, v);
        ec_edge<<<gb_n8, 256, 0, stream>>>(ec_val, ofs, (const __half*)u,
                                           (const __half*)v, x);
    }

    out_kernel<<<(NN + 255) / 256, 256, 0, stream>>>(x, ow, ob, out);
}